// Round 21
// baseline (32.786 us; speedup 1.0000x reference)
//
#include <hip/hip_runtime.h>
#include <hip/hip_fp16.h>
#include <math.h>

#define BB 16
#define CC 3
#define HH 512
#define WW 512
#define HW (HH * WW)
#define RAD 5
#define SEGV 16
#define NSEG (HH / SEGV)            // 32 segments per image
#define NSTRIP 3                    // 3 strips: 172,172,168 valid cols (lane-aligned)
#define NTASK (BB * NSEG * NSTRIP)  // 1536 wave-tasks = 1536 single-wave blocks
#define NBLK NTASK                  // 6 blocks/CU exactly
#define NITER (SEGV + 2 * RAD)      // 26 row iterations = 2 x 13
#define RINGD 13                    // ring depth 13 -> static indices in 13-unroll

// ---- DPP wave-shift helpers (VALU pipe, no DS) ----
#define DPP_WAVE_SHL1 0x130
#define DPP_WAVE_SHR1 0x138

template <int CTRL>
__device__ __forceinline__ float dpp_f(float x) {
    union { float f; int i; } u, o;
    u.f = x;
    o.i = __builtin_amdgcn_update_dpp(0, u.i, CTRL, 0xF, 0xF, true);
    return o.f;
}
template <int CTRL>
__device__ __forceinline__ __half2 dpp_h2(__half2 x) {
    union { __half2 h; int i; } u, o;
    u.h = x;
    o.i = __builtin_amdgcn_update_dpp(0, u.i, CTRL, 0xF, 0xF, true);
    return o.h;
}
#define SHL1F(x) dpp_f<DPP_WAVE_SHL1>(x)
#define SHR1F(x) dpp_f<DPP_WAVE_SHR1>(x)
#define SHL1H(x) dpp_h2<DPP_WAVE_SHL1>(x)
#define SHR1H(x) dpp_h2<DPP_WAVE_SHR1>(x)

__device__ __forceinline__ float2 f2add(float2 a, float2 b) {
    return make_float2(a.x + b.x, a.y + b.y);   // v_pk_add_f32
}
__device__ __forceinline__ float2 f2sub(float2 a, float2 b) {
    return make_float2(a.x - b.x, a.y - b.y);
}

// R20 structure (ring-13, outer rolled x2, I$-friendly) with an instruction
// diet: packed f32 running sums (v_pk_add_f32), pack-level masking, unmasked
// sq (guards already ensure validity). 4 cols/lane, DPP horizontal trees.
__global__ __launch_bounds__(64) void fused_q4s(
    const float* __restrict__ pred, const float* __restrict__ target,
    float* __restrict__ ws_sq, float* __restrict__ ws_cos)
{
    const int lane = threadIdx.x;

    // bijective XCD-contiguous swizzle (1536 % 8 == 0): 192 blocks/XCD
    const int bid = (int)blockIdx.x;
    const int swz = (bid & 7) * (NBLK / 8) + (bid >> 3);

    const int img   = swz / (NSEG * NSTRIP);
    const int rem   = swz % (NSEG * NSTRIP);
    const int seg   = rem / NSTRIP;
    const int strip = rem - seg * NSTRIP;

    const int y0      = seg * SEGV;
    const int colbase = strip * 172 - 8;                 // -8, 164, 336
    const int col0    = colbase + lane * 4;              // 16B aligned
    const int col0c   = min(max(col0, 0), WW - 4);
    const float mx = ((strip == 0 && lane < 2) ||
                      (strip == 2 && lane >= 44)) ? 0.f : 1.f;
    const bool vout = (lane >= 2) && (lane <= (strip == 2 ? 43 : 44));

    const long base = (long)img * (CC * HW);

    // depth-1 staging
    float4 P0, P1, P2, T0, T1, T2;
    {
        const int y  = y0 - RAD;
        const int yc = y < 0 ? 0 : y;
        const long off = base + (long)yc * WW + col0c;
        P0 = *(const float4*)(pred + off);
        P1 = *(const float4*)(pred + off + HW);
        P2 = *(const float4*)(pred + off + 2 * HW);
        T0 = *(const float4*)(target + off);
        T1 = *(const float4*)(target + off + HW);
        T2 = *(const float4*)(target + off + 2 * HW);
    }

    // rings (depth 13): 4 dp-packed + 2 T-packed per row
    __half2 rh0[RINGD], rh1[RINGD], rh2[RINGD], rh3[RINGD];
    __half2 rt01[RINGD], rt23[RINGD];
    // packed running sums: S_k = (Sd_k, Sp_k); STa = (St0, St1), STb = (St2, St3)
    float2 S0 = make_float2(0.f, 0.f), S1 = S0, S2 = S0, S3 = S0;
    float2 STa = S0, STb = S0;
    float sq = 0.f, cosacc = 0.f;

    #pragma unroll 1
    for (int o = 0; o < 2; ++o) {
        const int itbase = o * 13;
        #pragma unroll
        for (int i = 0; i < 13; ++i) {
            const int it = itbase + i;            // i static; o rolled
            const int y = y0 - RAD + it;
            const float msk = (y >= 0 && y < HH) ? mx : 0.f;

            const float4 p0=P0, p1=P1, p2=P2, t0=T0, t1=T1, t2=T2;
            if (it + 1 < NITER) {                 // prefetch next row
                const int y2  = y0 - RAD + it + 1;
                const int yc2 = min(max(y2, 0), HH - 1);
                const long off2 = base + (long)yc2 * WW + col0c;
                P0 = *(const float4*)(pred + off2);
                P1 = *(const float4*)(pred + off2 + HW);
                P2 = *(const float4*)(pred + off2 + 2 * HW);
                T0 = *(const float4*)(target + off2);
                T1 = *(const float4*)(target + off2 + HW);
                T2 = *(const float4*)(target + off2 + 2 * HW);
            }

            // per-pixel dot/pp/tt (UNMASKED; mask applied at pack level)
            const float d0=p0.x*t0.x+p1.x*t1.x+p2.x*t2.x;
            const float d1=p0.y*t0.y+p1.y*t1.y+p2.y*t2.y;
            const float d2=p0.z*t0.z+p1.z*t1.z+p2.z*t2.z;
            const float d3=p0.w*t0.w+p1.w*t1.w+p2.w*t2.w;
            const float q0=p0.x*p0.x+p1.x*p1.x+p2.x*p2.x;
            const float q1=p0.y*p0.y+p1.y*p1.y+p2.y*p2.y;
            const float q2=p0.z*p0.z+p1.z*p1.z+p2.z*p2.z;
            const float q3=p0.w*p0.w+p1.w*p1.w+p2.w*p2.w;
            const float u0r=t0.x*t0.x+t1.x*t1.x+t2.x*t2.x;
            const float u1r=t0.y*t0.y+t1.y*t1.y+t2.y*t2.y;
            const float u2r=t0.z*t0.z+t1.z*t1.z+t2.z*t2.z;
            const float u3r=t0.w*t0.w+t1.w*t1.w+t2.w*t2.w;

            // PSNR squared error: owned rows are always in-image, vout
            // excludes invalid cols -> no mask needed here.
            if (it >= RAD && it < RAD + SEGV && vout) {
                sq += (q0+u0r-2.f*d0)+(q1+u1r-2.f*d1)
                    + (q2+u2r-2.f*d2)+(q3+u3r-2.f*d3);
            }

            // masked values for window sums
            const __half2 mh = __floats2half2_rn(msk, msk);
            const float u0=u0r*msk, u1=u1r*msk, u2=u2r*msk, u3=u3r*msk;

            // ---- dp-packed horizontal tree (DPP) ----
            const __half2 A0 = __hmul2(__floats2half2_rn(d0, q0), mh);
            const __half2 B0 = __hmul2(__floats2half2_rn(d1, q1), mh);
            const __half2 A1 = __hmul2(__floats2half2_rn(d2, q2), mh);
            const __half2 B1 = __hmul2(__floats2half2_rn(d3, q3), mh);
            const __half2 pr0 = __hadd2(A0, B0);
            const __half2 pr1 = __hadd2(A1, B1);
            const __half2 prL = __hadd2(pr0, pr1);
            const __half2 s_prL_m1 = SHL1H(prL);
            const __half2 s_prL_p1 = SHR1H(prL);
            const __half2 s_pr0_p1 = SHR1H(pr0);
            const __half2 s_pr1_m1 = SHL1H(pr1);
            const __half2 s_B1_m2  = SHL1H(SHL1H(B1));
            const __half2 s_A1_p1  = SHR1H(A1);
            const __half2 s_B0_m1  = SHL1H(B0);
            const __half2 s_A0_p2  = SHR1H(SHR1H(A0));
            const __half2 S50 = __hadd2(__hadd2(s_prL_m1, prL), s_pr0_p1);
            const __half2 S51 = __hadd2(__hadd2(s_pr1_m1, prL), s_prL_p1);
            const __half2 h0 = __hadd2(s_B1_m2, S50);
            const __half2 h1 = __hadd2(S50, s_A1_p1);
            const __half2 h2 = __hadd2(s_B0_m1, S51);
            const __half2 h3 = __hadd2(S51, s_A0_p2);

            // ---- T tree (f32) ----
            const float prt0 = u0 + u1, prt1 = u2 + u3;
            const float prtL = prt0 + prt1;
            const float tL_m1 = SHL1F(prtL);
            const float tL_p1 = SHR1F(prtL);
            const float t0_p1 = SHR1F(prt0);
            const float t1_m1 = SHL1F(prt1);
            const float tB1m2 = SHL1F(SHL1F(u3));
            const float tA1p1 = SHR1F(u2);
            const float tB0m1 = SHL1F(u1);
            const float tA0p2 = SHR1F(SHR1F(u0));
            const float T50 = (tL_m1 + prtL) + t0_p1;
            const float T51 = (t1_m1 + prtL) + tL_p1;
            const __half2 ht01 = __floats2half2_rn(tB1m2 + T50, T50 + tA1p1);
            const __half2 ht23 = __floats2half2_rn(tB0m1 + T51, T51 + tA0p2);

            // accumulate QUANTIZED values (packed f32 adds) -> exact cancel
            S0  = f2add(S0,  __half22float2(h0));
            S1  = f2add(S1,  __half22float2(h1));
            S2  = f2add(S2,  __half22float2(h2));
            S3  = f2add(S3,  __half22float2(h3));
            STa = f2add(STa, __half22float2(ht01));
            STb = f2add(STb, __half22float2(ht23));

            if (it >= 10) {
                if (vout) {
                    cosacc += S0.x * rsqrtf(fmaxf(S0.y * STa.x, 1e-20f));
                    cosacc += S1.x * rsqrtf(fmaxf(S1.y * STa.y, 1e-20f));
                    cosacc += S2.x * rsqrtf(fmaxf(S2.y * STb.x, 1e-20f));
                    cosacc += S3.x * rsqrtf(fmaxf(S3.y * STb.y, 1e-20f));
                }
                const int sidx = (i + 3) % 13;     // slot of h(it-10), static
                S0  = f2sub(S0,  __half22float2(rh0[sidx]));
                S1  = f2sub(S1,  __half22float2(rh1[sidx]));
                S2  = f2sub(S2,  __half22float2(rh2[sidx]));
                S3  = f2sub(S3,  __half22float2(rh3[sidx]));
                STa = f2sub(STa, __half22float2(rt01[sidx]));
                STb = f2sub(STb, __half22float2(rt23[sidx]));
            }
            rh0[i] = h0;                           // write slot it%13 == i
            rh1[i] = h1;
            rh2[i] = h2;
            rh3[i] = h3;
            rt01[i] = ht01;
            rt23[i] = ht23;
        }
    }

    // wave reduce -> per-block (= per-wave) partial stores
    #pragma unroll
    for (int o = 32; o > 0; o >>= 1) {
        cosacc += __shfl_down(cosacc, o);
        sq     += __shfl_down(sq, o);
    }
    if (lane == 0) {
        ws_cos[swz] = cosacc;
        ws_sq [swz] = sq;
    }
}

// ---------------- finalize: 1536 sq + 1536 cos partials ----------------
__global__ __launch_bounds__(256) void finalize6(
    const float* __restrict__ ws_sq, const float* __restrict__ ws_cos,
    float* __restrict__ out)
{
    __shared__ float sq_b[16];
    __shared__ float cred[4];
    const int tid = threadIdx.x;

    // sq: 96 partials per image; 16 threads/image, 6 values each
    const int b = tid >> 4, j = tid & 15;
    float s = 0.f;
    #pragma unroll
    for (int k = 0; k < 6; ++k) s += ws_sq[b * 96 + j * 6 + k];
    #pragma unroll
    for (int o = 8; o > 0; o >>= 1) s += __shfl_down(s, o, 16);
    if (j == 0) sq_b[b] = s;

    float c = 0.f;
    #pragma unroll
    for (int k = 0; k < 6; ++k) c += ws_cos[tid + 256 * k];
    #pragma unroll
    for (int o = 32; o > 0; o >>= 1) c += __shfl_down(c, o);
    if ((tid & 63) == 0) cred[tid >> 6] = c;
    __syncthreads();

    if (tid == 0) {
        const float csum = cred[0] + cred[1] + cred[2] + cred[3];
        const float scale = 4.342944819032518f;   // 10 / ln(10)
        float lsum = 0.f;
        for (int bb = 0; bb < 16; ++bb)
            lsum += logf(sq_b[bb] / (float)(CC * HW) + 1e-8f);
        out[0] = scale * (lsum / (float)BB) + (1.f - csum / (float)(BB * HW));
    }
}

extern "C" void kernel_launch(void* const* d_in, const int* in_sizes, int n_in,
                              void* d_out, int out_size, void* d_ws, size_t ws_size,
                              hipStream_t stream)
{
    const float* pred   = (const float*)d_in[0];
    const float* target = (const float*)d_in[1];

    float* ws_sq  = (float*)d_ws;                        // 1536 floats
    float* ws_cos = (float*)((char*)d_ws + 8192);        // 1536 floats

    fused_q4s<<<dim3(NBLK), 64, 0, stream>>>(pred, target, ws_sq, ws_cos);
    finalize6<<<1, 256, 0, stream>>>(ws_sq, ws_cos, (float*)d_out);
}

// Round 22
// 26.264 us; speedup vs baseline: 1.2483x; 1.2483x over previous
//
#include <hip/hip_runtime.h>
#include <hip/hip_fp16.h>
#include <math.h>

#define BB 16
#define CC 3
#define HH 512
#define WW 512
#define HW (HH * WW)
#define RAD 5
#define SEGV 32
#define NSEG (HH / SEGV)            // 16 segments per image
#define NSTRIP 3                    // 3 strips: 172,172,168 valid cols (lane-aligned)
#define NTASK (BB * NSEG * NSTRIP)  // 768 wave-tasks = 768 single-wave blocks
#define NBLK NTASK                  // 3 blocks/CU exactly, 96/XCD = 2 images
#define NITER (SEGV + 2 * RAD)      // 42 row iterations = 3 x 14
#define RINGD 14                    // ring depth 14 -> static indices in 14-unroll

// ---- DPP wave-shift helpers (VALU pipe, no DS) ----
#define DPP_WAVE_SHL1 0x130
#define DPP_WAVE_SHR1 0x138

template <int CTRL>
__device__ __forceinline__ float dpp_f(float x) {
    union { float f; int i; } u, o;
    u.f = x;
    o.i = __builtin_amdgcn_update_dpp(0, u.i, CTRL, 0xF, 0xF, true);
    return o.f;
}
template <int CTRL>
__device__ __forceinline__ __half2 dpp_h2(__half2 x) {
    union { __half2 h; int i; } u, o;
    u.h = x;
    o.i = __builtin_amdgcn_update_dpp(0, u.i, CTRL, 0xF, 0xF, true);
    return o.h;
}
#define SHL1F(x) dpp_f<DPP_WAVE_SHL1>(x)
#define SHR1F(x) dpp_f<DPP_WAVE_SHR1>(x)
#define SHL1H(x) dpp_h2<DPP_WAVE_SHL1>(x)
#define SHR1H(x) dpp_h2<DPP_WAVE_SHR1>(x)

__device__ __forceinline__ float2 f2add(float2 a, float2 b) {
    return make_float2(a.x + b.x, a.y + b.y);   // v_pk_add_f32
}
__device__ __forceinline__ float2 f2sub(float2 a, float2 b) {
    return make_float2(a.x - b.x, a.y - b.y);
}

// R21 lean body at SEGV=32: vertical halo 1.625x -> 1.31x (-19% L3 bytes).
// Ring-14 (42 = 3x14) keeps all ring indices static inside the 14-unrolled
// inner loop with the outer rolled x3 (I$-resident, ~18KB — the R20 fix
// that R17's 42-wide full unroll lacked). 4 cols/lane, DPP trees.
__global__ __launch_bounds__(64) void fused_q4x(
    const float* __restrict__ pred, const float* __restrict__ target,
    float* __restrict__ ws_sq, float* __restrict__ ws_cos)
{
    const int lane = threadIdx.x;

    // bijective XCD-contiguous swizzle (768 % 8 == 0): 96 blocks/XCD
    const int bid = (int)blockIdx.x;
    const int swz = (bid & 7) * (NBLK / 8) + (bid >> 3);

    const int img   = swz / (NSEG * NSTRIP);
    const int rem   = swz % (NSEG * NSTRIP);
    const int seg   = rem / NSTRIP;
    const int strip = rem - seg * NSTRIP;

    const int y0      = seg * SEGV;
    const int colbase = strip * 172 - 8;                 // -8, 164, 336
    const int col0    = colbase + lane * 4;              // 16B aligned
    const int col0c   = min(max(col0, 0), WW - 4);
    const float mx = ((strip == 0 && lane < 2) ||
                      (strip == 2 && lane >= 44)) ? 0.f : 1.f;
    const bool vout = (lane >= 2) && (lane <= (strip == 2 ? 43 : 44));

    const long base = (long)img * (CC * HW);

    // depth-1 staging
    float4 P0, P1, P2, T0, T1, T2;
    {
        const int y  = y0 - RAD;
        const int yc = y < 0 ? 0 : y;
        const long off = base + (long)yc * WW + col0c;
        P0 = *(const float4*)(pred + off);
        P1 = *(const float4*)(pred + off + HW);
        P2 = *(const float4*)(pred + off + 2 * HW);
        T0 = *(const float4*)(target + off);
        T1 = *(const float4*)(target + off + HW);
        T2 = *(const float4*)(target + off + 2 * HW);
    }

    // rings (depth 14): 4 dp-packed + 2 T-packed per row
    __half2 rh0[RINGD], rh1[RINGD], rh2[RINGD], rh3[RINGD];
    __half2 rt01[RINGD], rt23[RINGD];
    float2 S0 = make_float2(0.f, 0.f), S1 = S0, S2 = S0, S3 = S0;
    float2 STa = S0, STb = S0;
    float sq = 0.f, cosacc = 0.f;

    #pragma unroll 1
    for (int o = 0; o < 3; ++o) {
        const int itbase = o * 14;
        #pragma unroll
        for (int i = 0; i < 14; ++i) {
            const int it = itbase + i;            // i static; o rolled
            const int y = y0 - RAD + it;
            const float msk = (y >= 0 && y < HH) ? mx : 0.f;

            const float4 p0=P0, p1=P1, p2=P2, t0=T0, t1=T1, t2=T2;
            if (it + 1 < NITER) {                 // prefetch next row
                const int y2  = y0 - RAD + it + 1;
                const int yc2 = min(max(y2, 0), HH - 1);
                const long off2 = base + (long)yc2 * WW + col0c;
                P0 = *(const float4*)(pred + off2);
                P1 = *(const float4*)(pred + off2 + HW);
                P2 = *(const float4*)(pred + off2 + 2 * HW);
                T0 = *(const float4*)(target + off2);
                T1 = *(const float4*)(target + off2 + HW);
                T2 = *(const float4*)(target + off2 + 2 * HW);
            }

            // per-pixel dot/pp/tt (UNMASKED; mask applied at pack level)
            const float d0=p0.x*t0.x+p1.x*t1.x+p2.x*t2.x;
            const float d1=p0.y*t0.y+p1.y*t1.y+p2.y*t2.y;
            const float d2=p0.z*t0.z+p1.z*t1.z+p2.z*t2.z;
            const float d3=p0.w*t0.w+p1.w*t1.w+p2.w*t2.w;
            const float q0=p0.x*p0.x+p1.x*p1.x+p2.x*p2.x;
            const float q1=p0.y*p0.y+p1.y*p1.y+p2.y*p2.y;
            const float q2=p0.z*p0.z+p1.z*p1.z+p2.z*p2.z;
            const float q3=p0.w*p0.w+p1.w*p1.w+p2.w*p2.w;
            const float u0r=t0.x*t0.x+t1.x*t1.x+t2.x*t2.x;
            const float u1r=t0.y*t0.y+t1.y*t1.y+t2.y*t2.y;
            const float u2r=t0.z*t0.z+t1.z*t1.z+t2.z*t2.z;
            const float u3r=t0.w*t0.w+t1.w*t1.w+t2.w*t2.w;

            // PSNR squared error: owned rows always in-image; vout guards cols
            if (it >= RAD && it < RAD + SEGV && vout) {
                sq += (q0+u0r-2.f*d0)+(q1+u1r-2.f*d1)
                    + (q2+u2r-2.f*d2)+(q3+u3r-2.f*d3);
            }

            // masked values for window sums
            const __half2 mh = __floats2half2_rn(msk, msk);
            const float u0=u0r*msk, u1=u1r*msk, u2=u2r*msk, u3=u3r*msk;

            // ---- dp-packed horizontal tree (DPP) ----
            const __half2 A0 = __hmul2(__floats2half2_rn(d0, q0), mh);
            const __half2 B0 = __hmul2(__floats2half2_rn(d1, q1), mh);
            const __half2 A1 = __hmul2(__floats2half2_rn(d2, q2), mh);
            const __half2 B1 = __hmul2(__floats2half2_rn(d3, q3), mh);
            const __half2 pr0 = __hadd2(A0, B0);
            const __half2 pr1 = __hadd2(A1, B1);
            const __half2 prL = __hadd2(pr0, pr1);
            const __half2 s_prL_m1 = SHL1H(prL);
            const __half2 s_prL_p1 = SHR1H(prL);
            const __half2 s_pr0_p1 = SHR1H(pr0);
            const __half2 s_pr1_m1 = SHL1H(pr1);
            const __half2 s_B1_m2  = SHL1H(SHL1H(B1));
            const __half2 s_A1_p1  = SHR1H(A1);
            const __half2 s_B0_m1  = SHL1H(B0);
            const __half2 s_A0_p2  = SHR1H(SHR1H(A0));
            const __half2 S50 = __hadd2(__hadd2(s_prL_m1, prL), s_pr0_p1);
            const __half2 S51 = __hadd2(__hadd2(s_pr1_m1, prL), s_prL_p1);
            const __half2 h0 = __hadd2(s_B1_m2, S50);
            const __half2 h1 = __hadd2(S50, s_A1_p1);
            const __half2 h2 = __hadd2(s_B0_m1, S51);
            const __half2 h3 = __hadd2(S51, s_A0_p2);

            // ---- T tree (f32) ----
            const float prt0 = u0 + u1, prt1 = u2 + u3;
            const float prtL = prt0 + prt1;
            const float tL_m1 = SHL1F(prtL);
            const float tL_p1 = SHR1F(prtL);
            const float t0_p1 = SHR1F(prt0);
            const float t1_m1 = SHL1F(prt1);
            const float tB1m2 = SHL1F(SHL1F(u3));
            const float tA1p1 = SHR1F(u2);
            const float tB0m1 = SHL1F(u1);
            const float tA0p2 = SHR1F(SHR1F(u0));
            const float T50 = (tL_m1 + prtL) + t0_p1;
            const float T51 = (t1_m1 + prtL) + tL_p1;
            const __half2 ht01 = __floats2half2_rn(tB1m2 + T50, T50 + tA1p1);
            const __half2 ht23 = __floats2half2_rn(tB0m1 + T51, T51 + tA0p2);

            // accumulate QUANTIZED values (packed f32 adds) -> exact cancel
            S0  = f2add(S0,  __half22float2(h0));
            S1  = f2add(S1,  __half22float2(h1));
            S2  = f2add(S2,  __half22float2(h2));
            S3  = f2add(S3,  __half22float2(h3));
            STa = f2add(STa, __half22float2(ht01));
            STb = f2add(STb, __half22float2(ht23));

            if (it >= 10) {
                if (vout) {
                    cosacc += S0.x * rsqrtf(fmaxf(S0.y * STa.x, 1e-20f));
                    cosacc += S1.x * rsqrtf(fmaxf(S1.y * STa.y, 1e-20f));
                    cosacc += S2.x * rsqrtf(fmaxf(S2.y * STb.x, 1e-20f));
                    cosacc += S3.x * rsqrtf(fmaxf(S3.y * STb.y, 1e-20f));
                }
                // subtract h(it-10): slot (it-10) mod 14 == (i+4)%14 (static)
                const int sidx = (i + 4) % 14;
                S0  = f2sub(S0,  __half22float2(rh0[sidx]));
                S1  = f2sub(S1,  __half22float2(rh1[sidx]));
                S2  = f2sub(S2,  __half22float2(rh2[sidx]));
                S3  = f2sub(S3,  __half22float2(rh3[sidx]));
                STa = f2sub(STa, __half22float2(rt01[sidx]));
                STb = f2sub(STb, __half22float2(rt23[sidx]));
            }
            rh0[i] = h0;                           // write slot it%14 == i
            rh1[i] = h1;
            rh2[i] = h2;
            rh3[i] = h3;
            rt01[i] = ht01;
            rt23[i] = ht23;
        }
    }

    // wave reduce -> per-block (= per-wave) partial stores
    #pragma unroll
    for (int o = 32; o > 0; o >>= 1) {
        cosacc += __shfl_down(cosacc, o);
        sq     += __shfl_down(sq, o);
    }
    if (lane == 0) {
        ws_cos[swz] = cosacc;
        ws_sq [swz] = sq;
    }
}

// ---------------- finalize: 768 sq + 768 cos partials ----------------
__global__ __launch_bounds__(256) void finalize7(
    const float* __restrict__ ws_sq, const float* __restrict__ ws_cos,
    float* __restrict__ out)
{
    __shared__ float sq_b[16];
    __shared__ float cred[4];
    const int tid = threadIdx.x;

    // sq: 48 partials per image; 16 threads/image, 3 values each
    const int b = tid >> 4, j = tid & 15;
    float s = 0.f;
    #pragma unroll
    for (int k = 0; k < 3; ++k) s += ws_sq[b * 48 + j * 3 + k];
    #pragma unroll
    for (int o = 8; o > 0; o >>= 1) s += __shfl_down(s, o, 16);
    if (j == 0) sq_b[b] = s;

    float c = ws_cos[tid] + ws_cos[tid + 256] + ws_cos[tid + 512];
    #pragma unroll
    for (int o = 32; o > 0; o >>= 1) c += __shfl_down(c, o);
    if ((tid & 63) == 0) cred[tid >> 6] = c;
    __syncthreads();

    if (tid == 0) {
        const float csum = cred[0] + cred[1] + cred[2] + cred[3];
        const float scale = 4.342944819032518f;   // 10 / ln(10)
        float lsum = 0.f;
        for (int bb = 0; bb < 16; ++bb)
            lsum += logf(sq_b[bb] / (float)(CC * HW) + 1e-8f);
        out[0] = scale * (lsum / (float)BB) + (1.f - csum / (float)(BB * HW));
    }
}

extern "C" void kernel_launch(void* const* d_in, const int* in_sizes, int n_in,
                              void* d_out, int out_size, void* d_ws, size_t ws_size,
                              hipStream_t stream)
{
    const float* pred   = (const float*)d_in[0];
    const float* target = (const float*)d_in[1];

    float* ws_sq  = (float*)d_ws;                        // 768 floats
    float* ws_cos = (float*)((char*)d_ws + 8192);        // 768 floats

    fused_q4x<<<dim3(NBLK), 64, 0, stream>>>(pred, target, ws_sq, ws_cos);
    finalize7<<<1, 256, 0, stream>>>(ws_sq, ws_cos, (float*)d_out);
}